// Round 16
// baseline (272.723 us; speedup 1.0000x reference)
//
#include <hip/hip_runtime.h>
#include <cstdint>
#include <cstddef>

#define S_LEN 2048
// 1/sqrt(192) * log2(e): scores in log2 domain -> exp2 softmax
#define SCALE_L2E (0.07216878364870323f * 1.4426950408889634f)

typedef __attribute__((ext_vector_type(8))) short short8;
typedef __attribute__((ext_vector_type(4))) float f32x4;
typedef __attribute__((ext_vector_type(16))) float f32x16;
typedef __attribute__((ext_vector_type(4))) unsigned short ushort4v;

__device__ __forceinline__ unsigned short f2bf(float f) {
  unsigned int u = __builtin_bit_cast(unsigned int, f);
  u += 0x7FFFu + ((u >> 16) & 1u);
  return (unsigned short)(u >> 16);
}
__device__ __forceinline__ float bf2f(unsigned short h) {
  unsigned int u = ((unsigned int)h) << 16;
  return __builtin_bit_cast(float, u);
}
__device__ __forceinline__ unsigned int cvt_pk_bf16(float lo, float hi) {
  unsigned int r;
  asm("v_cvt_pk_bf16_f32 %0, %1, %2" : "=v"(r) : "v"(lo), "v"(hi));
  return r;
}
// raw v_exp_f32 (exact exp2, 1 VALU op). libm exp2f w/o -ffast-math = ~6-op OCML path.
__device__ __forceinline__ float exp2_raw(float x) {
  return __builtin_amdgcn_exp2f(x);
}

typedef const __attribute__((address_space(1))) void* gas_ptr;
typedef __attribute__((address_space(3))) void* las_ptr;
__device__ __forceinline__ void gload16(const void* g, void* l) {
  __builtin_amdgcn_global_load_lds((gas_ptr)g, (las_ptr)l, 16, 0, 0);
}

// ---------------- shared device bodies ----------------

__device__ __forceinline__ void transpose_tile(
    const float* __restrict__ src, unsigned short* __restrict__ dst,
    int K, int N, int kb, int nb, unsigned short* tile) {
  const int tid = threadIdx.x;
  #pragma unroll
  for (int i = 0; i < 4; ++i) {
    int idx = i * 256 + tid;
    int row = idx >> 4, c4 = (idx & 15) << 2;
    const float4 v = *reinterpret_cast<const float4*>(&src[(size_t)(kb + row) * N + nb + c4]);
    tile[row * 72 + c4 + 0] = f2bf(v.x);
    tile[row * 72 + c4 + 1] = f2bf(v.y);
    tile[row * 72 + c4 + 2] = f2bf(v.z);
    tile[row * 72 + c4 + 3] = f2bf(v.w);
  }
  __syncthreads();
  #pragma unroll
  for (int i = 0; i < 4; ++i) {
    int idx = i * 256 + tid;
    int n = idx >> 4, kc = (idx & 15) << 2;
    ushort4v o = { tile[(kc + 0) * 72 + n], tile[(kc + 1) * 72 + n],
                   tile[(kc + 2) * 72 + n], tile[(kc + 3) * 72 + n] };
    *reinterpret_cast<ushort4v*>(&dst[(size_t)(nb + n) * K + kb + kc]) = o;
  }
}

// GEMM body: 128x128 tile, double-buffered gload_lds, XCD-chunked remap.
template <int MODE>
__device__ __forceinline__ void gemm_body(
    const unsigned short* __restrict__ A, const unsigned short* __restrict__ Bt,
    const float* __restrict__ bias, void* __restrict__ Cout,
    unsigned short* __restrict__ Vt, int N, int K, int lda, int ldc,
    int subId, int subN, int gx, unsigned short* SM) {
  unsigned short* As = SM;
  unsigned short* Bs = SM + 8192;
  const int tid = threadIdx.x;
  const int lane = tid & 63, wid = tid >> 6;
  const int wr = wid >> 1, wc = wid & 1;
  const int l = (subId & 7) * (subN >> 3) + (subId >> 3);
  const int m0 = (l / gx) << 7, n0 = (l % gx) << 7;
  const int l15 = lane & 15, g = lane >> 4;

  const int srow = (wid << 5) + (lane >> 2);
  const int scol = (lane & 3) << 3;
  const unsigned short* aptr0 = &A[(size_t)(m0 + srow) * lda + scol];
  const unsigned short* aptr1 = &A[(size_t)(m0 + srow + 16) * lda + scol];
  int br0 = n0 + srow;      if (br0 >= N) br0 = N - 1;
  int br1 = n0 + srow + 16; if (br1 >= N) br1 = N - 1;
  const unsigned short* bptr0 = &Bt[(size_t)br0 * K + scol];
  const unsigned short* bptr1 = &Bt[(size_t)br1 * K + scol];
  const int lofs0 = ((wid << 1) + 0) << 9;
  const int lofs1 = ((wid << 1) + 1) << 9;

  f32x4 acc[4][4];
  #pragma unroll
  for (int m = 0; m < 4; ++m)
    #pragma unroll
    for (int n = 0; n < 4; ++n) acc[m][n] = f32x4{0.f, 0.f, 0.f, 0.f};

  gload16(aptr0, &As[lofs0]);
  gload16(aptr1, &As[lofs1]);
  gload16(bptr0, &Bs[lofs0]);
  gload16(bptr1, &Bs[lofs1]);
  __syncthreads();

  int cur = 0;
  for (int k0 = 0; k0 < K; k0 += 32) {
    const int nxt = cur ^ 1;
    if (k0 + 32 < K) {
      gload16(aptr0 + k0 + 32, &As[nxt * 4096 + lofs0]);
      gload16(aptr1 + k0 + 32, &As[nxt * 4096 + lofs1]);
      gload16(bptr0 + k0 + 32, &Bs[nxt * 4096 + lofs0]);
      gload16(bptr1 + k0 + 32, &Bs[nxt * 4096 + lofs1]);
    }
    short8 af[4], bfr[4];
    #pragma unroll
    for (int m = 0; m < 4; ++m)
      af[m] = *reinterpret_cast<const short8*>(
          &As[cur * 4096 + (((wr << 6) + (m << 4) + l15) << 5) + (g << 3)]);
    #pragma unroll
    for (int n = 0; n < 4; ++n)
      bfr[n] = *reinterpret_cast<const short8*>(
          &Bs[cur * 4096 + (((wc << 6) + (n << 4) + l15) << 5) + (g << 3)]);
    __builtin_amdgcn_s_setprio(1);
    #pragma unroll
    for (int m = 0; m < 4; ++m)
      #pragma unroll
      for (int n = 0; n < 4; ++n)
        acc[m][n] = __builtin_amdgcn_mfma_f32_16x16x32_bf16(af[m], bfr[n], acc[m][n], 0, 0, 0);
    __builtin_amdgcn_s_setprio(0);
    __syncthreads();
    cur = nxt;
  }

  if (MODE == 2 && (n0 & 128)) {
    const int hh = n0 >> 8;
    const int bb = m0 >> 11;
    const int s0 = m0 & 2047;
    unsigned short* T = SM;
    #pragma unroll
    for (int pass = 0; pass < 2; ++pass) {
      __syncthreads();
      if (wc == pass) {
        #pragma unroll
        for (int n = 0; n < 4; ++n) {
          int c = (n << 4) + l15;
          float bv = bias[n0 + (pass << 6) + c];
          #pragma unroll
          for (int m = 0; m < 4; ++m) {
            int rb = (wr << 6) + (m << 4) + (g << 2);
            #pragma unroll
            for (int r = 0; r < 4; ++r)
              T[c * 130 + rb + r] = f2bf(acc[m][n][r] + bv);
          }
        }
      }
      __syncthreads();
      int c = tid >> 2, seg = tid & 3;
      const unsigned short* src = &T[c * 130 + (seg << 5)];
      unsigned int wbuf[16];
      #pragma unroll
      for (int i = 0; i < 16; ++i)
        wbuf[i] = *reinterpret_cast<const unsigned int*>(&src[i * 2]);
      int4* dst = reinterpret_cast<int4*>(
          &Vt[(((size_t)bb * 16 + hh) * 128 + (pass << 6) + c) * 2048 + s0 + (seg << 5)]);
      #pragma unroll
      for (int i = 0; i < 4; ++i) {
        int4 v;
        v.x = (int)wbuf[4 * i + 0]; v.y = (int)wbuf[4 * i + 1];
        v.z = (int)wbuf[4 * i + 2]; v.w = (int)wbuf[4 * i + 3];
        dst[i] = v;
      }
    }
    return;
  }

  #pragma unroll
  for (int n = 0; n < 4; ++n) {
    int col = n0 + (wc << 6) + (n << 4) + l15;
    if (col >= N) continue;
    float bv = bias[col];
    #pragma unroll
    for (int m = 0; m < 4; ++m) {
      int rowb = m0 + (wr << 6) + (m << 4) + (g << 2);
      #pragma unroll
      for (int r = 0; r < 4; ++r) {
        float v = acc[m][n][r] + bv;
        int row = rowb + r;
        if (MODE == 0) {
          reinterpret_cast<float*>(Cout)[(size_t)row * ldc + col] = v;
        } else if (MODE == 1) {
          reinterpret_cast<unsigned short*>(Cout)[(size_t)row * ldc + col] = f2bf(v);
        } else {
          int hh = col >> 8, dd = col & 255;
          reinterpret_cast<unsigned short*>(Cout)[(size_t)row * 2048 + hh * 128 + dd] = f2bf(v);
        }
      }
    }
  }
}

// GEMM body, 128x64 tile: 4 waves as 2(M)x2(N), 64x32 out/wave, acc 8xf32x4.
// Smaller tile -> more co-resident blocks (the 2-phase loop hides its barrier-drain
// via cross-block overlap; k_out's natural 128x128 grid was only 2 blocks/CU).
// LDS: As 2x[128][32] + Bs 2x[64][32] = 24 KB (shares the 32 KB SMEM decl).
template <int MODE>
__device__ __forceinline__ void gemm_body_n64(
    const unsigned short* __restrict__ A, const unsigned short* __restrict__ Bt,
    const float* __restrict__ bias, void* __restrict__ Cout,
    int N, int K, int lda, int ldc,
    int subId, int subN, int gx, unsigned short* SM) {
  unsigned short* As = SM;            // 2 x 4096 elems
  unsigned short* Bs = SM + 8192;     // 2 x 2048 elems
  const int tid = threadIdx.x;
  const int lane = tid & 63, wid = tid >> 6;
  const int wr = wid >> 1, wc = wid & 1;
  const int l = (subId & 7) * (subN >> 3) + (subId >> 3);
  const int m0 = (l / gx) << 7, n0 = (l % gx) << 6;
  const int l15 = lane & 15, g = lane >> 4;

  // A staging (128x32/tile): wave covers rows wid*32..+31 in two 16-row instrs
  const int srow = (wid << 5) + (lane >> 2);
  const int scol = (lane & 3) << 3;
  const unsigned short* aptr0 = &A[(size_t)(m0 + srow) * lda + scol];
  const unsigned short* aptr1 = &A[(size_t)(m0 + srow + 16) * lda + scol];
  // B staging (64x32/tile): wave covers rows wid*16..+15, one instr
  const int brow = (wid << 4) + (lane >> 2);
  int br = n0 + brow; if (br >= N) br = N - 1;
  const unsigned short* bptr = &Bt[(size_t)br * K + scol];
  const int lofsA0 = ((wid << 1) + 0) << 9;
  const int lofsA1 = ((wid << 1) + 1) << 9;
  const int lofsB  = wid << 9;  // wid*512 elems = 1KB/wave

  f32x4 acc[4][2];
  #pragma unroll
  for (int m = 0; m < 4; ++m)
    #pragma unroll
    for (int n = 0; n < 2; ++n) acc[m][n] = f32x4{0.f, 0.f, 0.f, 0.f};

  gload16(aptr0, &As[lofsA0]);
  gload16(aptr1, &As[lofsA1]);
  gload16(bptr, &Bs[lofsB]);
  __syncthreads();

  int cur = 0;
  for (int k0 = 0; k0 < K; k0 += 32) {
    const int nxt = cur ^ 1;
    if (k0 + 32 < K) {
      gload16(aptr0 + k0 + 32, &As[nxt * 4096 + lofsA0]);
      gload16(aptr1 + k0 + 32, &As[nxt * 4096 + lofsA1]);
      gload16(bptr + k0 + 32, &Bs[nxt * 2048 + lofsB]);
    }
    short8 af[4], bfr[2];
    #pragma unroll
    for (int m = 0; m < 4; ++m)
      af[m] = *reinterpret_cast<const short8*>(
          &As[cur * 4096 + (((wr << 6) + (m << 4) + l15) << 5) + (g << 3)]);
    #pragma unroll
    for (int n = 0; n < 2; ++n)
      bfr[n] = *reinterpret_cast<const short8*>(
          &Bs[cur * 2048 + (((wc << 5) + (n << 4) + l15) << 5) + (g << 3)]);
    __builtin_amdgcn_s_setprio(1);
    #pragma unroll
    for (int m = 0; m < 4; ++m)
      #pragma unroll
      for (int n = 0; n < 2; ++n)
        acc[m][n] = __builtin_amdgcn_mfma_f32_16x16x32_bf16(af[m], bfr[n], acc[m][n], 0, 0, 0);
    __builtin_amdgcn_s_setprio(0);
    __syncthreads();
    cur = nxt;
  }

  #pragma unroll
  for (int n = 0; n < 2; ++n) {
    int col = n0 + (wc << 5) + (n << 4) + l15;
    if (col >= N) continue;
    float bv = bias[col];
    #pragma unroll
    for (int m = 0; m < 4; ++m) {
      int rowb = m0 + (wr << 6) + (m << 4) + (g << 2);
      #pragma unroll
      for (int r = 0; r < 4; ++r) {
        float v = acc[m][n][r] + bv;
        int row = rowb + r;
        if (MODE == 0)
          reinterpret_cast<float*>(Cout)[(size_t)row * ldc + col] = v;
        else
          reinterpret_cast<unsigned short*>(Cout)[(size_t)row * ldc + col] = f2bf(v);
      }
    }
  }
}

// ---------------- launch-stage kernels ----------------

__global__ __launch_bounds__(256) void k_prep_a(
    const float* __restrict__ x, const float* __restrict__ freq,
    const float* __restrict__ wdq, const float* __restrict__ wdkv,
    const float* __restrict__ wkr,
    const float* __restrict__ b_uq, const float* __restrict__ b_qr,
    const float* __restrict__ b_dq, const float* __restrict__ b_dkv,
    const float* __restrict__ b_kr,
    unsigned short* __restrict__ x_bf, unsigned short* __restrict__ wd_t,
    float* __restrict__ tab, float* __restrict__ bcat, float* __restrict__ ball) {
  __shared__ __align__(16) unsigned short SMEM[64 * 72];
  const int bid = blockIdx.x;
  const int tid = threadIdx.x;
  if (bid < 384) {
    transpose_tile(wdq, wd_t, 2048, 768, (bid / 12) << 6, (bid % 12) << 6, SMEM);
  } else if (bid < 640) {
    int r = bid - 384;
    transpose_tile(wdkv, wd_t + (size_t)768 * 2048, 2048, 512, (r >> 3) << 6, (r & 7) << 6, SMEM);
  } else if (bid < 672) {
    int r = bid - 640;
    transpose_tile(wkr, wd_t + (size_t)1280 * 2048, 2048, 64, r << 6, 0, SMEM);
  } else if (bid < 8864) {
    int i = (bid - 672) * 256 + tid;
    const float4 v = reinterpret_cast<const float4*>(x)[i];
    ushort4v o = { f2bf(v.x), f2bf(v.y), f2bf(v.z), f2bf(v.w) };
    reinterpret_cast<ushort4v*>(x_bf)[i] = o;
  } else if (bid < 9120) {
    int i = (bid - 8864) * 256 + tid;
    float f = freq[i];
    tab[2 * i] = cosf(f);
    tab[2 * i + 1] = sinf(f);
  } else {
    int i = (bid - 9120) * 256 + tid;
    if (i < 2048) bcat[i] = b_uq[i];
    else if (i < 3072) bcat[i] = b_qr[i - 2048];
    else if (i < 3840) ball[i - 3072] = b_dq[i - 3072];
    else if (i < 4352) ball[i - 3072] = b_dkv[i - 3840];
    else if (i < 4416) ball[i - 3072] = b_kr[i - 4352];
  }
}

__global__ __launch_bounds__(256) void k_down(
    const unsigned short* __restrict__ x_bf, const unsigned short* __restrict__ wd_t,
    const float* __restrict__ ball, unsigned short* __restrict__ c_all,
    const float* __restrict__ wuq, const float* __restrict__ wqr,
    const float* __restrict__ wukv, const float* __restrict__ wo,
    unsigned short* __restrict__ wqc_t, unsigned short* __restrict__ wukv_t,
    unsigned short* __restrict__ wo_t) {
  __shared__ __align__(16) unsigned short SMEM[16384];
  const int bid = blockIdx.x;
  if (bid < 352) {
    gemm_body<1>(x_bf, wd_t, ball, c_all, nullptr, 1344, 2048, 2048, 1344,
                 bid, 352, 11, SMEM);
  } else if (bid < 736) {
    int r = bid - 352;
    transpose_tile(wuq, wqc_t, 768, 2048, (r >> 5) << 6, (r & 31) << 6, SMEM);
  } else if (bid < 928) {
    int r = bid - 736;
    transpose_tile(wqr, wqc_t + (size_t)2048 * 768, 768, 1024, (r >> 4) << 6, (r & 15) << 6, SMEM);
  } else if (bid < 1440) {
    int r = bid - 928;
    transpose_tile(wukv, wukv_t, 512, 4096, (r >> 6) << 6, (r & 63) << 6, SMEM);
  } else {
    int r = bid - 1440;
    transpose_tile(wo, wo_t, 2048, 2048, (r >> 5) << 6, (r & 31) << 6, SMEM);
  }
}

// stage C: upQ GEMM (128x64 tiles, 1536) + upKV split GEMM (1024) + rope_kr (512)
__global__ __launch_bounds__(256) void k_up(
    const unsigned short* __restrict__ c_all, const unsigned short* __restrict__ wqc_t,
    const float* __restrict__ bcat, unsigned short* __restrict__ q_raw,
    const unsigned short* __restrict__ wukv_t, const float* __restrict__ b_ukv,
    unsigned short* __restrict__ kc, unsigned short* __restrict__ v_t,
    const float* __restrict__ tab, unsigned short* __restrict__ krro) {
  __shared__ __align__(16) unsigned short SMEM[16384];
  const int bid = blockIdx.x;
  if (bid < 1536) {
    gemm_body_n64<1>(c_all, wqc_t, bcat, q_raw, 3072, 768, 1344, 3072,
                     bid, 1536, 48, SMEM);
  } else if (bid < 2560) {
    gemm_body<2>(c_all + 768, wukv_t, b_ukv, kc, v_t, 4096, 512, 1344, 2048,
                 bid - 1536, 1024, 32, SMEM);
  } else {
    int idx = (bid - 2560) * 256 + threadIdx.x;
    if (idx < 4096 * 32) {
      int bs = idx >> 5, p = idx & 31;
      int s = bs & (S_LEN - 1);
      float c = tab[(s * 32 + p) * 2], sn = tab[(s * 32 + p) * 2 + 1];
      float x1 = bf2f(c_all[(size_t)bs * 1344 + 1280 + 2 * p]);
      float x2 = bf2f(c_all[(size_t)bs * 1344 + 1280 + 2 * p + 1]);
      krro[bs * 64 + 2 * p] = f2bf(x1 * c - x2 * sn);
      krro[bs * 64 + 2 * p + 1] = f2bf(x1 * sn + x2 * c);
    }
  }
}

// stage E: output projection -> f32; 128x64 tiles -> 1024 blocks = 4/CU
__global__ __launch_bounds__(256) void k_out(
    const unsigned short* __restrict__ attn, const unsigned short* __restrict__ wo_t,
    const float* __restrict__ b_o, float* __restrict__ out) {
  __shared__ __align__(16) unsigned short SMEM[16384];
  gemm_body_n64<0>(attn, wo_t, b_o, out, 2048, 2048, 2048, 2048,
                   (int)blockIdx.x, 1024, 32, SMEM);
}

// ---------------- fused causal flash attention (32x32 MFMA, KVBLK=64/wave) -------------
// grid 512, block 512 = 8 waves: 4 q-strips (s) x 2 KV-parity groups (e).
// Per iteration each parity group processes a PAIR of tiles {4u+2e, 4u+2e+1} in two
// SEPARATE guarded blocks (round-13 config, best-known: 90us, VGPR 124, no spill).
// LESSON (round 14): merging the pair keeps 64 extra f32 live -> VGPR cap 128 ->
// scratch spill -> +5us. This kernel sits AT the register cliff.
// Reg-staged write-late staging (no global_load_lds): sync = lgkmcnt(0)+s_barrier only.
__global__ __launch_bounds__(512, 2) void k_mla_attn(
    const unsigned short* __restrict__ q_raw, const unsigned short* __restrict__ kc,
    const unsigned short* __restrict__ v_t, const unsigned short* __restrict__ krro,
    const float* __restrict__ tab, unsigned short* __restrict__ attn_out) {
  __shared__ __align__(16) unsigned char smem[151552];
  unsigned short* KcB = reinterpret_cast<unsigned short*>(smem);            // 8 x [32][136]
  unsigned short* VtB = reinterpret_cast<unsigned short*>(smem + 69632);    // 8 x [128][40]
  float* Msh = reinterpret_cast<float*>(smem);  // merge scratch (post-loop reuse)

  const int tid = threadIdx.x;
  const int lane = tid & 63, w = tid >> 6;
  const int s = w & 3, e = w >> 2;
  const int l31 = lane & 31, hi = lane >> 5;
  const int hi8 = hi << 3;
  const int bid = blockIdx.x;
  const int bh = bid & 31, b = bh >> 4, h = bh & 15;
  const int uu = (bid >> 5) & 7;
  const int chunk = (bid >> 8) ? (15 - uu) : uu;
  const size_t bsb = (size_t)b * S_LEN;

  const int krow0 = (s << 3) + (lane >> 4);
  const int kunit = lane & 15;
  const unsigned short* kcbase = &kc[bsb * 2048 + h * 128 + kunit * 8];
  const int vd = (w << 4) + (lane >> 2);
  const int vu = lane & 3;
  const unsigned short* vtbase = &v_t[((size_t)(b * 16 + h) * 128 + vd) * 2048 + vu * 8];

  const int q0 = (chunk << 7) + (s << 5);
  const int srow = q0 + l31;
  const int U = chunk + 1;            // iterations; tiles = 4U
  const int nt_w = (q0 + 63) >> 5;

  // ---- Q fragments, pre-scaled by SCALE*log2e ----
  short8 qf[12];
  {
    const size_t qrow = (bsb + q0 + l31) * 3072;
    #pragma unroll
    for (int ks = 0; ks < 8; ++ks) {
      short8 rv = *reinterpret_cast<const short8*>(&q_raw[qrow + h * 128 + ks * 16 + hi8]);
      union { unsigned short us[8]; short8 v; } uq;
      #pragma unroll
      for (int j = 0; j < 8; ++j)
        uq.us[j] = f2bf(bf2f((unsigned short)rv[j]) * SCALE_L2E);
      qf[ks] = uq.v;
    }
    #pragma unroll
    for (int f = 0; f < 4; ++f) {
      short8 rv = *reinterpret_cast<const short8*>(
          &q_raw[qrow + 2048 + h * 64 + f * 16 + hi8]);
      int pi0 = 8 * f + 4 * hi;
      union { unsigned short us[8]; short8 v; } uq;
      #pragma unroll
      for (int j = 0; j < 4; ++j) {
        float c = tab[(srow * 32 + pi0 + j) * 2];
        float sn = tab[(srow * 32 + pi0 + j) * 2 + 1];
        float x1 = bf2f((unsigned short)rv[2 * j]);
        float x2 = bf2f((unsigned short)rv[2 * j + 1]);
        uq.us[2 * j] = f2bf((x1 * c - x2 * sn) * SCALE_L2E);
        uq.us[2 * j + 1] = f2bf((x1 * sn + x2 * c) * SCALE_L2E);
      }
      qf[8 + f] = uq.v;
    }
  }

  f32x16 acc[4];
  #pragma unroll
  for (int a = 0; a < 4; ++a)
    #pragma unroll
    for (int r = 0; r < 16; ++r) acc[a][r] = 0.f;
  float mrun = -1e30f, lsum = 0.f;

  // per-tile process (QK + online softmax + PV); wave-uniform caller guard on t
  auto process_tile = [&](int t, const short8* krf) {
    const int kvb = t << 5;
    const int kbuf = t & 7;
    f32x16 sca, scb;
    #pragma unroll
    for (int r = 0; r < 16; ++r) { sca[r] = 0.f; scb[r] = 0.f; }
    __builtin_amdgcn_s_setprio(1);
    #pragma unroll
    for (int j = 0; j < 4; ++j) {
      short8 k0 = *reinterpret_cast<const short8*>(
          &KcB[kbuf * 4352 + l31 * 136 + (((j << 2) | hi) << 3)]);
      sca = __builtin_amdgcn_mfma_f32_32x32x16_bf16(k0, qf[2 * j], sca, 0, 0, 0);
      short8 k1 = *reinterpret_cast<const short8*>(
          &KcB[kbuf * 4352 + l31 * 136 + ((((j << 2) + 2) | hi) << 3)]);
      scb = __builtin_amdgcn_mfma_f32_32x32x16_bf16(k1, qf[2 * j + 1], scb, 0, 0, 0);
    }
    sca = __builtin_amdgcn_mfma_f32_32x32x16_bf16(krf[0], qf[8], sca, 0, 0, 0);
    scb = __builtin_amdgcn_mfma_f32_32x32x16_bf16(krf[1], qf[9], scb, 0, 0, 0);
    sca = __builtin_amdgcn_mfma_f32_32x32x16_bf16(krf[2], qf[10], sca, 0, 0, 0);
    scb = __builtin_amdgcn_mfma_f32_32x32x16_bf16(krf[3], qf[11], scb, 0, 0, 0);
    __builtin_amdgcn_s_setprio(0);
    f32x16 sc = sca + scb;

    if (kvb + 31 > q0) {
      #pragma unroll
      for (int r = 0; r < 16; ++r) {
        int kv = kvb + (r & 3) + ((r >> 2) << 3) + (hi << 2);
        if (kv > srow) sc[r] = -1e30f;
      }
    }
    float m0 = fmaxf(fmaxf(sc[0], sc[1]), fmaxf(sc[2], sc[3]));
    float m1 = fmaxf(fmaxf(sc[4], sc[5]), fmaxf(sc[6], sc[7]));
    float m2 = fmaxf(fmaxf(sc[8], sc[9]), fmaxf(sc[10], sc[11]));
    float m3 = fmaxf(fmaxf(sc[12], sc[13]), fmaxf(sc[14], sc[15]));
    float tmax = fmaxf(fmaxf(m0, m1), fmaxf(m2, m3));
    tmax = fmaxf(tmax, __shfl_xor(tmax, 32));

    bool rescale = !__all(tmax <= mrun + 8.f);
    float scold = 1.f;
    if (rescale) {
      float mm = fmaxf(mrun, tmax);
      scold = exp2_raw(mrun - mm);
      mrun = mm;
    }
    float pe[16];
    float ts = 0.f;
    #pragma unroll
    for (int r = 0; r < 16; ++r) { pe[r] = exp2_raw(sc[r] - mrun); ts += pe[r]; }
    ts += __shfl_xor(ts, 32);
    lsum = lsum * scold + ts;

    if (rescale) {
      #pragma unroll
      for (int a = 0; a < 4; ++a)
        #pragma unroll
        for (int r = 0; r < 16; ++r) acc[a][r] *= scold;
    }
    #pragma unroll
    for (int ks = 0; ks < 2; ++ks) {
      unsigned int X0 = cvt_pk_bf16(pe[8 * ks + 0], pe[8 * ks + 1]);
      unsigned int X1 = cvt_pk_bf16(pe[8 * ks + 2], pe[8 * ks + 3]);
      unsigned int Y0 = cvt_pk_bf16(pe[8 * ks + 4], pe[8 * ks + 5]);
      unsigned int Y1 = cvt_pk_bf16(pe[8 * ks + 6], pe[8 * ks + 7]);
      unsigned int send0 = hi ? X0 : Y0;
      unsigned int send1 = hi ? X1 : Y1;
      unsigned int recv0 = (unsigned int)__shfl_xor((int)send0, 32);
      unsigned int recv1 = (unsigned int)__shfl_xor((int)send1, 32);
      union { unsigned int u[4]; short8 v; } pa;
      pa.u[0] = hi ? recv0 : X0;
      pa.u[1] = hi ? recv1 : X1;
      pa.u[2] = hi ? Y0 : recv0;
      pa.u[3] = hi ? Y1 : recv1;
      __builtin_amdgcn_s_setprio(1);
      #pragma unroll
      for (int a = 0; a < 4; ++a) {
        short8 va = *reinterpret_cast<const short8*>(
            &VtB[kbuf * 5120 + ((a << 5) + l31) * 40 + (((ks << 1) | hi) << 3)]);
        acc[a] = __builtin_amdgcn_mfma_f32_32x32x16_bf16(va, pa.v, acc[a], 0, 0, 0);
      }
      __builtin_amdgcn_s_setprio(0);
    }
  };

  int4 kcur0a, kcur0b, kcur1a, kcur1b;   // K regs for tiles {4(u+1)+2e, +1}
  int4 vcur0, vcur1, vcur2, vcur3;       // V regs for tiles {4(u+1)..4(u+1)+3}
  // ---- prologue: tiles 0..3 to LDS (via regs); preload regs for tiles 4..7 ----
  {
    const int t0 = 2 * e, t1 = 2 * e + 1;
    int4 a0 = *reinterpret_cast<const int4*>(&kcbase[(size_t)((t0 << 5) + krow0) * 2048]);
    int4 a1 = *reinterpret_cast<const int4*>(&kcbase[(size_t)((t0 << 5) + krow0 + 4) * 2048]);
    int4 b0 = *reinterpret_cast<const int4*>(&kcbase[(size_t)((t1 << 5) + krow0) * 2048]);
    int4 b1 = *reinterpret_cast<const int4*>(&kcbase[(size_t)((t1 << 5) + krow0 + 4) * 2048]);
    int4 v0 = *reinterpret_cast<const int4*>(&vtbase[0 << 5]);
    int4 v1 = *reinterpret_cast<const int4*>(&vtbase[1 << 5]);
    int4 v2 = *reinterpret_cast<const int4*>(&vtbase[2 << 5]);
    int4 v3 = *reinterpret_cast<const int4*>(&vtbase[3 << 5]);
    *reinterpret_cast<int4*>(&KcB[(t0 & 7) * 4352 + krow0 * 136 + kunit * 8]) = a0;
    *reinterpret_cast<int4*>(&KcB[(t0 & 7) * 4352 + (krow0 + 4) * 136 + kunit * 8]) = a1;
    *reinterpret_cast<int4*>(&KcB[(t1 & 7) * 4352 + krow0 * 136 + kunit * 8]) = b0;
    *reinterpret_cast<int4*>(&KcB[(t1 & 7) * 4352 + (krow0 + 4) * 136 + kunit * 8]) = b1;
    *reinterpret_cast<int4*>(&VtB[0 * 5120 + vd * 40 + vu * 8]) = v0;
    *reinterpret_cast<int4*>(&VtB[1 * 5120 + vd * 40 + vu * 8]) = v1;
    *reinterpret_cast<int4*>(&VtB[2 * 5120 + vd * 40 + vu * 8]) = v2;
    *reinterpret_cast<int4*>(&VtB[3 * 5120 + vd * 40 + vu * 8]) = v3;
    const int n0t = 4 + 2 * e, n1t = 5 + 2 * e;
    kcur0a = *reinterpret_cast<const int4*>(&kcbase[(size_t)((n0t << 5) + krow0) * 2048]);
    kcur0b = *reinterpret_cast<const int4*>(&kcbase[(size_t)((n0t << 5) + krow0 + 4) * 2048]);
    kcur1a = *reinterpret_cast<const int4*>(&kcbase[(size_t)((n1t << 5) + krow0) * 2048]);
    kcur1b = *reinterpret_cast<const int4*>(&kcbase[(size_t)((n1t << 5) + krow0 + 4) * 2048]);
    vcur0 = *reinterpret_cast<const int4*>(&vtbase[4 << 5]);
    vcur1 = *reinterpret_cast<const int4*>(&vtbase[5 << 5]);
    vcur2 = *reinterpret_cast<const int4*>(&vtbase[6 << 5]);
    vcur3 = *reinterpret_cast<const int4*>(&vtbase[7 << 5]);
  }
  __syncthreads();

  for (int u = 0; u < U; ++u) {
    // 1. write staged regs: K tiles {4u+4+2e, 4u+5+2e}, V tiles {4u+4..4u+7}
    {
      const int wk0 = (4 * u + 4 + 2 * e) & 7, wk1 = (4 * u + 5 + 2 * e) & 7;
      *reinterpret_cast<int4*>(&KcB[wk0 * 4352 + krow0 * 136 + kunit * 8]) = kcur0a;
      *reinterpret_cast<int4*>(&KcB[wk0 * 4352 + (krow0 + 4) * 136 + kunit * 8]) = kcur0b;
      *reinterpret_cast<int4*>(&KcB[wk1 * 4352 + krow0 * 136 + kunit * 8]) = kcur1a;
      *reinterpret_cast<int4*>(&KcB[wk1 * 4352 + (krow0 + 4) * 136 + kunit * 8]) = kcur1b;
      const int wv = (4 * u + 4) & 7;
      *reinterpret_cast<int4*>(&VtB[wv * 5120 + vd * 40 + vu * 8]) = vcur0;
      *reinterpret_cast<int4*>(&VtB[((wv + 1) & 7) * 5120 + vd * 40 + vu * 8]) = vcur1;
      *reinterpret_cast<int4*>(&VtB[((wv + 2) & 7) * 5120 + vd * 40 + vu * 8]) = vcur2;
      *reinterpret_cast<int4*>(&VtB[((wv + 3) & 7) * 5120 + vd * 40 + vu * 8]) = vcur3;
    }
    // 2. issue next reg loads (clamped): K tiles {4u+8+2e, 4u+9+2e}, V {4u+8..4u+11}
    {
      int t0 = 4 * u + 8 + 2 * e; if (t0 > 63) t0 = 63;
      int t1 = 4 * u + 9 + 2 * e; if (t1 > 63) t1 = 63;
      kcur0a = *reinterpret_cast<const int4*>(&kcbase[(size_t)((t0 << 5) + krow0) * 2048]);
      kcur0b = *reinterpret_cast<const int4*>(&kcbase[(size_t)((t0 << 5) + krow0 + 4) * 2048]);
      kcur1a = *reinterpret_cast<const int4*>(&kcbase[(size_t)((t1 << 5) + krow0) * 2048]);
      kcur1b = *reinterpret_cast<const int4*>(&kcbase[(size_t)((t1 << 5) + krow0 + 4) * 2048]);
      int tv0 = 4 * u + 8;  if (tv0 > 63) tv0 = 63;
      int tv1 = 4 * u + 9;  if (tv1 > 63) tv1 = 63;
      int tv2 = 4 * u + 10; if (tv2 > 63) tv2 = 63;
      int tv3 = 4 * u + 11; if (tv3 > 63) tv3 = 63;
      vcur0 = *reinterpret_cast<const int4*>(&vtbase[tv0 << 5]);
      vcur1 = *reinterpret_cast<const int4*>(&vtbase[tv1 << 5]);
      vcur2 = *reinterpret_cast<const int4*>(&vtbase[tv2 << 5]);
      vcur3 = *reinterpret_cast<const int4*>(&vtbase[tv3 << 5]);
    }
    // 3/4. subtile A then B (separate guarded blocks; krro loaded on demand)
    {
      const int tA = 4 * u + 2 * e;
      if (tA < nt_w) {
        short8 krfA[4];
        #pragma unroll
        for (int f = 0; f < 4; ++f)
          krfA[f] = *reinterpret_cast<const short8*>(
              &krro[(bsb + (tA << 5) + l31) * 64 + f * 16 + hi8]);
        process_tile(tA, krfA);
      }
      const int tB = tA + 1;
      if (tB < nt_w) {
        short8 krfB[4];
        #pragma unroll
        for (int f = 0; f < 4; ++f)
          krfB[f] = *reinterpret_cast<const short8*>(
              &krro[(bsb + (tB << 5) + l31) * 64 + f * 16 + hi8]);
        process_tile(tB, krfB);
      }
    }
    // 5. sync: LDS writes visible; in-flight register loads cross the barrier
    asm volatile("s_waitcnt lgkmcnt(0)" ::: "memory");
    __builtin_amdgcn_s_barrier();
  }

  __syncthreads();  // full drain before LDS reuse as merge scratch

  // ---- flash merge of parity groups; acc = O^T[v][q=l31], m/l lane-local ----
  if (e == 1) {
    #pragma unroll
    for (int a = 0; a < 4; ++a)
      #pragma unroll
      for (int r = 0; r < 16; ++r) {
        int v = 32 * a + (r & 3) + ((r >> 2) << 3) + (hi << 2);
        Msh[((s << 7) + v) * 33 + l31] = acc[a][r];
      }
    if (hi == 0) {
      Msh[16896 + ((s << 5) + l31) * 2 + 0] = mrun;
      Msh[16896 + ((s << 5) + l31) * 2 + 1] = lsum;
    }
  }
  __syncthreads();
  if (e == 0) {
    float m1 = Msh[16896 + ((s << 5) + l31) * 2 + 0];
    float l1 = Msh[16896 + ((s << 5) + l31) * 2 + 1];
    float mm = fmaxf(mrun, m1);
    float ea = exp2_raw(mrun - mm), eb = exp2_raw(m1 - mm);
    float linv = 1.f / (lsum * ea + l1 * eb);
    float al = ea * linv, be = eb * linv;
    #pragma unroll
    for (int a = 0; a < 4; ++a)
      #pragma unroll
      for (int r = 0; r < 16; ++r) {
        int v = 32 * a + (r & 3) + ((r >> 2) << 3) + (hi << 2);
        float part = Msh[((s << 7) + v) * 33 + l31];
        acc[a][r] = acc[a][r] * al + part * be;
      }
    unsigned int* Tb = reinterpret_cast<unsigned int*>(smem) + s * 4224;
    #pragma unroll
    for (int a = 0; a < 4; ++a)
      #pragma unroll
      for (int j = 0; j < 8; ++j) {
        unsigned int word = cvt_pk_bf16(acc[a][2 * j], acc[a][2 * j + 1]);
        int wc = 16 * a + 2 * hi + (j & 1) + 4 * (j >> 1);
        Tb[l31 * 68 + wc] = word;
      }
    const unsigned char* Tbb = reinterpret_cast<const unsigned char*>(Tb);
    #pragma unroll
    for (int u2 = 0; u2 < 8; ++u2) {
      int qr = (u2 << 2) + (lane >> 4);
      int4 rd = *reinterpret_cast<const int4*>(&Tbb[qr * 272 + (lane & 15) * 16]);
      *reinterpret_cast<int4*>(
          &attn_out[(bsb + q0 + qr) * 2048 + h * 128 + (lane & 15) * 8]) = rd;
    }
  }
}

// ---------------- launch ----------------

extern "C" void kernel_launch(void* const* d_in, const int* in_sizes, int n_in,
                              void* d_out, int out_size, void* d_ws, size_t ws_size,
                              hipStream_t stream) {
  (void)in_sizes; (void)n_in; (void)out_size; (void)ws_size;
  const float* x = (const float*)d_in[0];
  const float* freq = (const float*)d_in[1];
  // d_in[2] = mask: always causal tril -> handled analytically
  const float* w_dq = (const float*)d_in[3];
  const float* b_dq = (const float*)d_in[4];
  const float* w_uq = (const float*)d_in[5];
  const float* b_uq = (const float*)d_in[6];
  const float* w_qr = (const float*)d_in[7];
  const float* b_qr = (const float*)d_in[8];
  const float* w_dkv = (const float*)d_in[9];
  const float* b_dkv = (const float*)d_in[10];
  const float* w_ukv = (const float*)d_in[11];
  const float* b_ukv = (const float*)d_in[12];
  const float* w_kr = (const float*)d_in[13];
  const float* b_kr = (const float*)d_in[14];
  const float* w_o = (const float*)d_in[15];
  const float* b_o = (const float*)d_in[16];

  char* ws = (char*)d_ws;
  size_t off = 0;
  auto alloc = [&](size_t bytes) {
    char* p = ws + off;
    off += (bytes + 255) & ~(size_t)255;
    return p;
  };
  unsigned short* x_bf   = (unsigned short*)alloc((size_t)4096 * 2048 * 2);
  unsigned short* wd_t   = (unsigned short*)alloc((size_t)1344 * 2048 * 2);
  unsigned short* wqc_t  = (unsigned short*)alloc((size_t)3072 * 768 * 2);
  unsigned short* wukv_t = (unsigned short*)alloc((size_t)4096 * 512 * 2);
  unsigned short* wo_t   = (unsigned short*)alloc((size_t)2048 * 2048 * 2);
  float* tab             = (float*)alloc((size_t)2048 * 32 * 2 * 4);
  float* bcat            = (float*)alloc((size_t)3072 * 4);
  float* ball            = (float*)alloc((size_t)1344 * 4);
  unsigned short* c_all  = (unsigned short*)alloc((size_t)4096 * 1344 * 2);
  unsigned short* krro   = (unsigned short*)alloc((size_t)4096 * 64 * 2);
  unsigned short* q_raw  = (unsigned short*)alloc((size_t)4096 * 3072 * 2);
  unsigned short* kc     = (unsigned short*)alloc((size_t)4096 * 2048 * 2);
  unsigned short* v_t    = (unsigned short*)alloc((size_t)4096 * 2048 * 2);
  unsigned short* attn   = (unsigned short*)alloc((size_t)4096 * 2048 * 2);

  // A: x cast + down-proj weight transposes + rope table + bias concat
  k_prep_a<<<dim3(9138), dim3(256), 0, stream>>>(
      x, freq, w_dq, w_dkv, w_kr, b_uq, b_qr, b_dq, b_dkv, b_kr,
      x_bf, wd_t, tab, bcat, ball);

  // B: merged down-projection GEMM + up/out weight transposes (tail-filled)
  k_down<<<dim3(2464), dim3(256), 0, stream>>>(
      x_bf, wd_t, ball, c_all, w_uq, w_qr, w_ukv, w_o, wqc_t, wukv_t, wo_t);

  // C: upQ GEMM (128x64 tiles) + upKV split GEMM + rope_kr
  k_up<<<dim3(3072), dim3(256), 0, stream>>>(
      c_all, wqc_t, bcat, q_raw, wukv_t, b_ukv, kc, v_t, tab, krro);

  // D: fused causal attention (round-13 best-known config)
  k_mla_attn<<<dim3(512), dim3(512), 0, stream>>>(q_raw, kc, v_t, krro, tab, attn);

  // E: output projection -> f32 (128x64 tiles, 4 blocks/CU)
  k_out<<<dim3(1024), dim3(256), 0, stream>>>(attn, wo_t, b_o, (float*)d_out);
}

// Round 17
// 246.713 us; speedup vs baseline: 1.1054x; 1.1054x over previous
//
#include <hip/hip_runtime.h>
#include <cstdint>
#include <cstddef>

#define S_LEN 2048
// 1/sqrt(192) * log2(e): scores in log2 domain -> exp2 softmax
#define SCALE_L2E (0.07216878364870323f * 1.4426950408889634f)

typedef __attribute__((ext_vector_type(8))) short short8;
typedef __attribute__((ext_vector_type(4))) float f32x4;
typedef __attribute__((ext_vector_type(16))) float f32x16;
typedef __attribute__((ext_vector_type(4))) unsigned short ushort4v;

__device__ __forceinline__ unsigned short f2bf(float f) {
  unsigned int u = __builtin_bit_cast(unsigned int, f);
  u += 0x7FFFu + ((u >> 16) & 1u);
  return (unsigned short)(u >> 16);
}
__device__ __forceinline__ float bf2f(unsigned short h) {
  unsigned int u = ((unsigned int)h) << 16;
  return __builtin_bit_cast(float, u);
}
__device__ __forceinline__ unsigned int cvt_pk_bf16(float lo, float hi) {
  unsigned int r;
  asm("v_cvt_pk_bf16_f32 %0, %1, %2" : "=v"(r) : "v"(lo), "v"(hi));
  return r;
}
// raw v_exp_f32 (exact exp2, 1 VALU op). libm exp2f w/o -ffast-math = ~6-op OCML path.
__device__ __forceinline__ float exp2_raw(float x) {
  return __builtin_amdgcn_exp2f(x);
}

typedef const __attribute__((address_space(1))) void* gas_ptr;
typedef __attribute__((address_space(3))) void* las_ptr;
__device__ __forceinline__ void gload16(const void* g, void* l) {
  __builtin_amdgcn_global_load_lds((gas_ptr)g, (las_ptr)l, 16, 0, 0);
}

// ---------------- shared device bodies ----------------

__device__ __forceinline__ void transpose_tile(
    const float* __restrict__ src, unsigned short* __restrict__ dst,
    int K, int N, int kb, int nb, unsigned short* tile) {
  const int tid = threadIdx.x;
  #pragma unroll
  for (int i = 0; i < 4; ++i) {
    int idx = i * 256 + tid;
    int row = idx >> 4, c4 = (idx & 15) << 2;
    const float4 v = *reinterpret_cast<const float4*>(&src[(size_t)(kb + row) * N + nb + c4]);
    tile[row * 72 + c4 + 0] = f2bf(v.x);
    tile[row * 72 + c4 + 1] = f2bf(v.y);
    tile[row * 72 + c4 + 2] = f2bf(v.z);
    tile[row * 72 + c4 + 3] = f2bf(v.w);
  }
  __syncthreads();
  #pragma unroll
  for (int i = 0; i < 4; ++i) {
    int idx = i * 256 + tid;
    int n = idx >> 4, kc = (idx & 15) << 2;
    ushort4v o = { tile[(kc + 0) * 72 + n], tile[(kc + 1) * 72 + n],
                   tile[(kc + 2) * 72 + n], tile[(kc + 3) * 72 + n] };
    *reinterpret_cast<ushort4v*>(&dst[(size_t)(nb + n) * K + kb + kc]) = o;
  }
}

// GEMM body: 128x128 tile, double-buffered gload_lds, XCD-chunked remap.
// NOTE (round 16): 128x64 tiles regressed +25us (halved B-reuse + halved MFMA/barrier);
// 128x128 2-phase is the validated local optimum for these shapes.
template <int MODE>
__device__ __forceinline__ void gemm_body(
    const unsigned short* __restrict__ A, const unsigned short* __restrict__ Bt,
    const float* __restrict__ bias, void* __restrict__ Cout,
    unsigned short* __restrict__ Vt, int N, int K, int lda, int ldc,
    int subId, int subN, int gx, unsigned short* SM) {
  unsigned short* As = SM;
  unsigned short* Bs = SM + 8192;
  const int tid = threadIdx.x;
  const int lane = tid & 63, wid = tid >> 6;
  const int wr = wid >> 1, wc = wid & 1;
  const int l = (subId & 7) * (subN >> 3) + (subId >> 3);
  const int m0 = (l / gx) << 7, n0 = (l % gx) << 7;
  const int l15 = lane & 15, g = lane >> 4;

  const int srow = (wid << 5) + (lane >> 2);
  const int scol = (lane & 3) << 3;
  const unsigned short* aptr0 = &A[(size_t)(m0 + srow) * lda + scol];
  const unsigned short* aptr1 = &A[(size_t)(m0 + srow + 16) * lda + scol];
  int br0 = n0 + srow;      if (br0 >= N) br0 = N - 1;
  int br1 = n0 + srow + 16; if (br1 >= N) br1 = N - 1;
  const unsigned short* bptr0 = &Bt[(size_t)br0 * K + scol];
  const unsigned short* bptr1 = &Bt[(size_t)br1 * K + scol];
  const int lofs0 = ((wid << 1) + 0) << 9;
  const int lofs1 = ((wid << 1) + 1) << 9;

  f32x4 acc[4][4];
  #pragma unroll
  for (int m = 0; m < 4; ++m)
    #pragma unroll
    for (int n = 0; n < 4; ++n) acc[m][n] = f32x4{0.f, 0.f, 0.f, 0.f};

  gload16(aptr0, &As[lofs0]);
  gload16(aptr1, &As[lofs1]);
  gload16(bptr0, &Bs[lofs0]);
  gload16(bptr1, &Bs[lofs1]);
  __syncthreads();

  int cur = 0;
  for (int k0 = 0; k0 < K; k0 += 32) {
    const int nxt = cur ^ 1;
    if (k0 + 32 < K) {
      gload16(aptr0 + k0 + 32, &As[nxt * 4096 + lofs0]);
      gload16(aptr1 + k0 + 32, &As[nxt * 4096 + lofs1]);
      gload16(bptr0 + k0 + 32, &Bs[nxt * 4096 + lofs0]);
      gload16(bptr1 + k0 + 32, &Bs[nxt * 4096 + lofs1]);
    }
    short8 af[4], bfr[4];
    #pragma unroll
    for (int m = 0; m < 4; ++m)
      af[m] = *reinterpret_cast<const short8*>(
          &As[cur * 4096 + (((wr << 6) + (m << 4) + l15) << 5) + (g << 3)]);
    #pragma unroll
    for (int n = 0; n < 4; ++n)
      bfr[n] = *reinterpret_cast<const short8*>(
          &Bs[cur * 4096 + (((wc << 6) + (n << 4) + l15) << 5) + (g << 3)]);
    __builtin_amdgcn_s_setprio(1);
    #pragma unroll
    for (int m = 0; m < 4; ++m)
      #pragma unroll
      for (int n = 0; n < 4; ++n)
        acc[m][n] = __builtin_amdgcn_mfma_f32_16x16x32_bf16(af[m], bfr[n], acc[m][n], 0, 0, 0);
    __builtin_amdgcn_s_setprio(0);
    __syncthreads();
    cur = nxt;
  }

  if (MODE == 2 && (n0 & 128)) {
    const int hh = n0 >> 8;
    const int bb = m0 >> 11;
    const int s0 = m0 & 2047;
    unsigned short* T = SM;
    #pragma unroll
    for (int pass = 0; pass < 2; ++pass) {
      __syncthreads();
      if (wc == pass) {
        #pragma unroll
        for (int n = 0; n < 4; ++n) {
          int c = (n << 4) + l15;
          float bv = bias[n0 + (pass << 6) + c];
          #pragma unroll
          for (int m = 0; m < 4; ++m) {
            int rb = (wr << 6) + (m << 4) + (g << 2);
            #pragma unroll
            for (int r = 0; r < 4; ++r)
              T[c * 130 + rb + r] = f2bf(acc[m][n][r] + bv);
          }
        }
      }
      __syncthreads();
      int c = tid >> 2, seg = tid & 3;
      const unsigned short* src = &T[c * 130 + (seg << 5)];
      unsigned int wbuf[16];
      #pragma unroll
      for (int i = 0; i < 16; ++i)
        wbuf[i] = *reinterpret_cast<const unsigned int*>(&src[i * 2]);
      int4* dst = reinterpret_cast<int4*>(
          &Vt[(((size_t)bb * 16 + hh) * 128 + (pass << 6) + c) * 2048 + s0 + (seg << 5)]);
      #pragma unroll
      for (int i = 0; i < 4; ++i) {
        int4 v;
        v.x = (int)wbuf[4 * i + 0]; v.y = (int)wbuf[4 * i + 1];
        v.z = (int)wbuf[4 * i + 2]; v.w = (int)wbuf[4 * i + 3];
        dst[i] = v;
      }
    }
    return;
  }

  #pragma unroll
  for (int n = 0; n < 4; ++n) {
    int col = n0 + (wc << 6) + (n << 4) + l15;
    if (col >= N) continue;
    float bv = bias[col];
    #pragma unroll
    for (int m = 0; m < 4; ++m) {
      int rowb = m0 + (wr << 6) + (m << 4) + (g << 2);
      #pragma unroll
      for (int r = 0; r < 4; ++r) {
        float v = acc[m][n][r] + bv;
        int row = rowb + r;
        if (MODE == 0) {
          reinterpret_cast<float*>(Cout)[(size_t)row * ldc + col] = v;
        } else if (MODE == 1) {
          reinterpret_cast<unsigned short*>(Cout)[(size_t)row * ldc + col] = f2bf(v);
        } else {
          int hh = col >> 8, dd = col & 255;
          reinterpret_cast<unsigned short*>(Cout)[(size_t)row * 2048 + hh * 128 + dd] = f2bf(v);
        }
      }
    }
  }
}

// ---------------- launch-stage kernels ----------------

__global__ __launch_bounds__(256) void k_prep_a(
    const float* __restrict__ x, const float* __restrict__ freq,
    const float* __restrict__ wdq, const float* __restrict__ wdkv,
    const float* __restrict__ wkr,
    const float* __restrict__ b_uq, const float* __restrict__ b_qr,
    const float* __restrict__ b_dq, const float* __restrict__ b_dkv,
    const float* __restrict__ b_kr,
    unsigned short* __restrict__ x_bf, unsigned short* __restrict__ wd_t,
    float* __restrict__ tab, float* __restrict__ bcat, float* __restrict__ ball) {
  __shared__ __align__(16) unsigned short SMEM[64 * 72];
  const int bid = blockIdx.x;
  const int tid = threadIdx.x;
  if (bid < 384) {
    transpose_tile(wdq, wd_t, 2048, 768, (bid / 12) << 6, (bid % 12) << 6, SMEM);
  } else if (bid < 640) {
    int r = bid - 384;
    transpose_tile(wdkv, wd_t + (size_t)768 * 2048, 2048, 512, (r >> 3) << 6, (r & 7) << 6, SMEM);
  } else if (bid < 672) {
    int r = bid - 640;
    transpose_tile(wkr, wd_t + (size_t)1280 * 2048, 2048, 64, r << 6, 0, SMEM);
  } else if (bid < 8864) {
    int i = (bid - 672) * 256 + tid;
    const float4 v = reinterpret_cast<const float4*>(x)[i];
    ushort4v o = { f2bf(v.x), f2bf(v.y), f2bf(v.z), f2bf(v.w) };
    reinterpret_cast<ushort4v*>(x_bf)[i] = o;
  } else if (bid < 9120) {
    int i = (bid - 8864) * 256 + tid;
    float f = freq[i];
    tab[2 * i] = cosf(f);
    tab[2 * i + 1] = sinf(f);
  } else {
    int i = (bid - 9120) * 256 + tid;
    if (i < 2048) bcat[i] = b_uq[i];
    else if (i < 3072) bcat[i] = b_qr[i - 2048];
    else if (i < 3840) ball[i - 3072] = b_dq[i - 3072];
    else if (i < 4352) ball[i - 3072] = b_dkv[i - 3840];
    else if (i < 4416) ball[i - 3072] = b_kr[i - 4352];
  }
}

__global__ __launch_bounds__(256) void k_down(
    const unsigned short* __restrict__ x_bf, const unsigned short* __restrict__ wd_t,
    const float* __restrict__ ball, unsigned short* __restrict__ c_all,
    const float* __restrict__ wuq, const float* __restrict__ wqr,
    const float* __restrict__ wukv, const float* __restrict__ wo,
    unsigned short* __restrict__ wqc_t, unsigned short* __restrict__ wukv_t,
    unsigned short* __restrict__ wo_t) {
  __shared__ __align__(16) unsigned short SMEM[16384];
  const int bid = blockIdx.x;
  if (bid < 352) {
    gemm_body<1>(x_bf, wd_t, ball, c_all, nullptr, 1344, 2048, 2048, 1344,
                 bid, 352, 11, SMEM);
  } else if (bid < 736) {
    int r = bid - 352;
    transpose_tile(wuq, wqc_t, 768, 2048, (r >> 5) << 6, (r & 31) << 6, SMEM);
  } else if (bid < 928) {
    int r = bid - 736;
    transpose_tile(wqr, wqc_t + (size_t)2048 * 768, 768, 1024, (r >> 4) << 6, (r & 15) << 6, SMEM);
  } else if (bid < 1440) {
    int r = bid - 928;
    transpose_tile(wukv, wukv_t, 512, 4096, (r >> 6) << 6, (r & 63) << 6, SMEM);
  } else {
    int r = bid - 1440;
    transpose_tile(wo, wo_t, 2048, 2048, (r >> 5) << 6, (r & 31) << 6, SMEM);
  }
}

__global__ __launch_bounds__(256) void k_up(
    const unsigned short* __restrict__ c_all, const unsigned short* __restrict__ wqc_t,
    const float* __restrict__ bcat, unsigned short* __restrict__ q_raw,
    const unsigned short* __restrict__ wukv_t, const float* __restrict__ b_ukv,
    unsigned short* __restrict__ kc, unsigned short* __restrict__ v_t,
    const float* __restrict__ tab, unsigned short* __restrict__ krro) {
  __shared__ __align__(16) unsigned short SMEM[16384];
  const int bid = blockIdx.x;
  if (bid < 768) {
    gemm_body<1>(c_all, wqc_t, bcat, q_raw, nullptr, 3072, 768, 1344, 3072,
                 bid, 768, 24, SMEM);
  } else if (bid < 1792) {
    gemm_body<2>(c_all + 768, wukv_t, b_ukv, kc, v_t, 4096, 512, 1344, 2048,
                 bid - 768, 1024, 32, SMEM);
  } else {
    int idx = (bid - 1792) * 256 + threadIdx.x;
    if (idx < 4096 * 32) {
      int bs = idx >> 5, p = idx & 31;
      int s = bs & (S_LEN - 1);
      float c = tab[(s * 32 + p) * 2], sn = tab[(s * 32 + p) * 2 + 1];
      float x1 = bf2f(c_all[(size_t)bs * 1344 + 1280 + 2 * p]);
      float x2 = bf2f(c_all[(size_t)bs * 1344 + 1280 + 2 * p + 1]);
      krro[bs * 64 + 2 * p] = f2bf(x1 * c - x2 * sn);
      krro[bs * 64 + 2 * p + 1] = f2bf(x1 * sn + x2 * c);
    }
  }
}

__global__ __launch_bounds__(256) void k_out(
    const unsigned short* __restrict__ attn, const unsigned short* __restrict__ wo_t,
    const float* __restrict__ b_o, float* __restrict__ out) {
  __shared__ __align__(16) unsigned short SMEM[16384];
  gemm_body<0>(attn, wo_t, b_o, out, nullptr, 2048, 2048, 2048, 2048,
               (int)blockIdx.x, 512, 16, SMEM);
}

// ---------------- fused causal flash attention (32x32 MFMA, KVBLK=64/wave) -------------
// grid 512, block 512 = 8 waves: 4 q-strips (s) x 2 KV-parity groups (e).
// Per iteration each parity group processes a PAIR of tiles {4u+2e, 4u+2e+1} in two
// SEPARATE guarded blocks (round-13 config, best-known: 90us, VGPR 124, no spill).
// LESSON (round 14): merging the pair keeps 64 extra f32 live -> VGPR cap 128 ->
// scratch spill -> +5us. This kernel sits AT the register cliff.
// Reg-staged write-late staging (no global_load_lds): sync = lgkmcnt(0)+s_barrier only.
__global__ __launch_bounds__(512, 2) void k_mla_attn(
    const unsigned short* __restrict__ q_raw, const unsigned short* __restrict__ kc,
    const unsigned short* __restrict__ v_t, const unsigned short* __restrict__ krro,
    const float* __restrict__ tab, unsigned short* __restrict__ attn_out) {
  __shared__ __align__(16) unsigned char smem[151552];
  unsigned short* KcB = reinterpret_cast<unsigned short*>(smem);            // 8 x [32][136]
  unsigned short* VtB = reinterpret_cast<unsigned short*>(smem + 69632);    // 8 x [128][40]
  float* Msh = reinterpret_cast<float*>(smem);  // merge scratch (post-loop reuse)

  const int tid = threadIdx.x;
  const int lane = tid & 63, w = tid >> 6;
  const int s = w & 3, e = w >> 2;
  const int l31 = lane & 31, hi = lane >> 5;
  const int hi8 = hi << 3;
  const int bid = blockIdx.x;
  const int bh = bid & 31, b = bh >> 4, h = bh & 15;
  const int uu = (bid >> 5) & 7;
  const int chunk = (bid >> 8) ? (15 - uu) : uu;
  const size_t bsb = (size_t)b * S_LEN;

  const int krow0 = (s << 3) + (lane >> 4);
  const int kunit = lane & 15;
  const unsigned short* kcbase = &kc[bsb * 2048 + h * 128 + kunit * 8];
  const int vd = (w << 4) + (lane >> 2);
  const int vu = lane & 3;
  const unsigned short* vtbase = &v_t[((size_t)(b * 16 + h) * 128 + vd) * 2048 + vu * 8];

  const int q0 = (chunk << 7) + (s << 5);
  const int srow = q0 + l31;
  const int U = chunk + 1;            // iterations; tiles = 4U
  const int nt_w = (q0 + 63) >> 5;

  // ---- Q fragments, pre-scaled by SCALE*log2e ----
  short8 qf[12];
  {
    const size_t qrow = (bsb + q0 + l31) * 3072;
    #pragma unroll
    for (int ks = 0; ks < 8; ++ks) {
      short8 rv = *reinterpret_cast<const short8*>(&q_raw[qrow + h * 128 + ks * 16 + hi8]);
      union { unsigned short us[8]; short8 v; } uq;
      #pragma unroll
      for (int j = 0; j < 8; ++j)
        uq.us[j] = f2bf(bf2f((unsigned short)rv[j]) * SCALE_L2E);
      qf[ks] = uq.v;
    }
    #pragma unroll
    for (int f = 0; f < 4; ++f) {
      short8 rv = *reinterpret_cast<const short8*>(
          &q_raw[qrow + 2048 + h * 64 + f * 16 + hi8]);
      int pi0 = 8 * f + 4 * hi;
      union { unsigned short us[8]; short8 v; } uq;
      #pragma unroll
      for (int j = 0; j < 4; ++j) {
        float c = tab[(srow * 32 + pi0 + j) * 2];
        float sn = tab[(srow * 32 + pi0 + j) * 2 + 1];
        float x1 = bf2f((unsigned short)rv[2 * j]);
        float x2 = bf2f((unsigned short)rv[2 * j + 1]);
        uq.us[2 * j] = f2bf((x1 * c - x2 * sn) * SCALE_L2E);
        uq.us[2 * j + 1] = f2bf((x1 * sn + x2 * c) * SCALE_L2E);
      }
      qf[8 + f] = uq.v;
    }
  }

  f32x16 acc[4];
  #pragma unroll
  for (int a = 0; a < 4; ++a)
    #pragma unroll
    for (int r = 0; r < 16; ++r) acc[a][r] = 0.f;
  float mrun = -1e30f, lsum = 0.f;

  // per-tile process (QK + online softmax + PV); wave-uniform caller guard on t
  auto process_tile = [&](int t, const short8* krf) {
    const int kvb = t << 5;
    const int kbuf = t & 7;
    f32x16 sca, scb;
    #pragma unroll
    for (int r = 0; r < 16; ++r) { sca[r] = 0.f; scb[r] = 0.f; }
    __builtin_amdgcn_s_setprio(1);
    #pragma unroll
    for (int j = 0; j < 4; ++j) {
      short8 k0 = *reinterpret_cast<const short8*>(
          &KcB[kbuf * 4352 + l31 * 136 + (((j << 2) | hi) << 3)]);
      sca = __builtin_amdgcn_mfma_f32_32x32x16_bf16(k0, qf[2 * j], sca, 0, 0, 0);
      short8 k1 = *reinterpret_cast<const short8*>(
          &KcB[kbuf * 4352 + l31 * 136 + ((((j << 2) + 2) | hi) << 3)]);
      scb = __builtin_amdgcn_mfma_f32_32x32x16_bf16(k1, qf[2 * j + 1], scb, 0, 0, 0);
    }
    sca = __builtin_amdgcn_mfma_f32_32x32x16_bf16(krf[0], qf[8], sca, 0, 0, 0);
    scb = __builtin_amdgcn_mfma_f32_32x32x16_bf16(krf[1], qf[9], scb, 0, 0, 0);
    sca = __builtin_amdgcn_mfma_f32_32x32x16_bf16(krf[2], qf[10], sca, 0, 0, 0);
    scb = __builtin_amdgcn_mfma_f32_32x32x16_bf16(krf[3], qf[11], scb, 0, 0, 0);
    __builtin_amdgcn_s_setprio(0);
    f32x16 sc = sca + scb;

    if (kvb + 31 > q0) {
      #pragma unroll
      for (int r = 0; r < 16; ++r) {
        int kv = kvb + (r & 3) + ((r >> 2) << 3) + (hi << 2);
        if (kv > srow) sc[r] = -1e30f;
      }
    }
    float m0 = fmaxf(fmaxf(sc[0], sc[1]), fmaxf(sc[2], sc[3]));
    float m1 = fmaxf(fmaxf(sc[4], sc[5]), fmaxf(sc[6], sc[7]));
    float m2 = fmaxf(fmaxf(sc[8], sc[9]), fmaxf(sc[10], sc[11]));
    float m3 = fmaxf(fmaxf(sc[12], sc[13]), fmaxf(sc[14], sc[15]));
    float tmax = fmaxf(fmaxf(m0, m1), fmaxf(m2, m3));
    tmax = fmaxf(tmax, __shfl_xor(tmax, 32));

    bool rescale = !__all(tmax <= mrun + 8.f);
    float scold = 1.f;
    if (rescale) {
      float mm = fmaxf(mrun, tmax);
      scold = exp2_raw(mrun - mm);
      mrun = mm;
    }
    float pe[16];
    float ts = 0.f;
    #pragma unroll
    for (int r = 0; r < 16; ++r) { pe[r] = exp2_raw(sc[r] - mrun); ts += pe[r]; }
    ts += __shfl_xor(ts, 32);
    lsum = lsum * scold + ts;

    if (rescale) {
      #pragma unroll
      for (int a = 0; a < 4; ++a)
        #pragma unroll
        for (int r = 0; r < 16; ++r) acc[a][r] *= scold;
    }
    #pragma unroll
    for (int ks = 0; ks < 2; ++ks) {
      unsigned int X0 = cvt_pk_bf16(pe[8 * ks + 0], pe[8 * ks + 1]);
      unsigned int X1 = cvt_pk_bf16(pe[8 * ks + 2], pe[8 * ks + 3]);
      unsigned int Y0 = cvt_pk_bf16(pe[8 * ks + 4], pe[8 * ks + 5]);
      unsigned int Y1 = cvt_pk_bf16(pe[8 * ks + 6], pe[8 * ks + 7]);
      unsigned int send0 = hi ? X0 : Y0;
      unsigned int send1 = hi ? X1 : Y1;
      unsigned int recv0 = (unsigned int)__shfl_xor((int)send0, 32);
      unsigned int recv1 = (unsigned int)__shfl_xor((int)send1, 32);
      union { unsigned int u[4]; short8 v; } pa;
      pa.u[0] = hi ? recv0 : X0;
      pa.u[1] = hi ? recv1 : X1;
      pa.u[2] = hi ? Y0 : recv0;
      pa.u[3] = hi ? Y1 : recv1;
      __builtin_amdgcn_s_setprio(1);
      #pragma unroll
      for (int a = 0; a < 4; ++a) {
        short8 va = *reinterpret_cast<const short8*>(
            &VtB[kbuf * 5120 + ((a << 5) + l31) * 40 + (((ks << 1) | hi) << 3)]);
        acc[a] = __builtin_amdgcn_mfma_f32_32x32x16_bf16(va, pa.v, acc[a], 0, 0, 0);
      }
      __builtin_amdgcn_s_setprio(0);
    }
  };

  int4 kcur0a, kcur0b, kcur1a, kcur1b;   // K regs for tiles {4(u+1)+2e, +1}
  int4 vcur0, vcur1, vcur2, vcur3;       // V regs for tiles {4(u+1)..4(u+1)+3}
  // ---- prologue: tiles 0..3 to LDS (via regs); preload regs for tiles 4..7 ----
  {
    const int t0 = 2 * e, t1 = 2 * e + 1;
    int4 a0 = *reinterpret_cast<const int4*>(&kcbase[(size_t)((t0 << 5) + krow0) * 2048]);
    int4 a1 = *reinterpret_cast<const int4*>(&kcbase[(size_t)((t0 << 5) + krow0 + 4) * 2048]);
    int4 b0 = *reinterpret_cast<const int4*>(&kcbase[(size_t)((t1 << 5) + krow0) * 2048]);
    int4 b1 = *reinterpret_cast<const int4*>(&kcbase[(size_t)((t1 << 5) + krow0 + 4) * 2048]);
    int4 v0 = *reinterpret_cast<const int4*>(&vtbase[0 << 5]);
    int4 v1 = *reinterpret_cast<const int4*>(&vtbase[1 << 5]);
    int4 v2 = *reinterpret_cast<const int4*>(&vtbase[2 << 5]);
    int4 v3 = *reinterpret_cast<const int4*>(&vtbase[3 << 5]);
    *reinterpret_cast<int4*>(&KcB[(t0 & 7) * 4352 + krow0 * 136 + kunit * 8]) = a0;
    *reinterpret_cast<int4*>(&KcB[(t0 & 7) * 4352 + (krow0 + 4) * 136 + kunit * 8]) = a1;
    *reinterpret_cast<int4*>(&KcB[(t1 & 7) * 4352 + krow0 * 136 + kunit * 8]) = b0;
    *reinterpret_cast<int4*>(&KcB[(t1 & 7) * 4352 + (krow0 + 4) * 136 + kunit * 8]) = b1;
    *reinterpret_cast<int4*>(&VtB[0 * 5120 + vd * 40 + vu * 8]) = v0;
    *reinterpret_cast<int4*>(&VtB[1 * 5120 + vd * 40 + vu * 8]) = v1;
    *reinterpret_cast<int4*>(&VtB[2 * 5120 + vd * 40 + vu * 8]) = v2;
    *reinterpret_cast<int4*>(&VtB[3 * 5120 + vd * 40 + vu * 8]) = v3;
    const int n0t = 4 + 2 * e, n1t = 5 + 2 * e;
    kcur0a = *reinterpret_cast<const int4*>(&kcbase[(size_t)((n0t << 5) + krow0) * 2048]);
    kcur0b = *reinterpret_cast<const int4*>(&kcbase[(size_t)((n0t << 5) + krow0 + 4) * 2048]);
    kcur1a = *reinterpret_cast<const int4*>(&kcbase[(size_t)((n1t << 5) + krow0) * 2048]);
    kcur1b = *reinterpret_cast<const int4*>(&kcbase[(size_t)((n1t << 5) + krow0 + 4) * 2048]);
    vcur0 = *reinterpret_cast<const int4*>(&vtbase[4 << 5]);
    vcur1 = *reinterpret_cast<const int4*>(&vtbase[5 << 5]);
    vcur2 = *reinterpret_cast<const int4*>(&vtbase[6 << 5]);
    vcur3 = *reinterpret_cast<const int4*>(&vtbase[7 << 5]);
  }
  __syncthreads();

  for (int u = 0; u < U; ++u) {
    // 1. write staged regs: K tiles {4u+4+2e, 4u+5+2e}, V tiles {4u+4..4u+7}
    {
      const int wk0 = (4 * u + 4 + 2 * e) & 7, wk1 = (4 * u + 5 + 2 * e) & 7;
      *reinterpret_cast<int4*>(&KcB[wk0 * 4352 + krow0 * 136 + kunit * 8]) = kcur0a;
      *reinterpret_cast<int4*>(&KcB[wk0 * 4352 + (krow0 + 4) * 136 + kunit * 8]) = kcur0b;
      *reinterpret_cast<int4*>(&KcB[wk1 * 4352 + krow0 * 136 + kunit * 8]) = kcur1a;
      *reinterpret_cast<int4*>(&KcB[wk1 * 4352 + (krow0 + 4) * 136 + kunit * 8]) = kcur1b;
      const int wv = (4 * u + 4) & 7;
      *reinterpret_cast<int4*>(&VtB[wv * 5120 + vd * 40 + vu * 8]) = vcur0;
      *reinterpret_cast<int4*>(&VtB[((wv + 1) & 7) * 5120 + vd * 40 + vu * 8]) = vcur1;
      *reinterpret_cast<int4*>(&VtB[((wv + 2) & 7) * 5120 + vd * 40 + vu * 8]) = vcur2;
      *reinterpret_cast<int4*>(&VtB[((wv + 3) & 7) * 5120 + vd * 40 + vu * 8]) = vcur3;
    }
    // 2. issue next reg loads (clamped): K tiles {4u+8+2e, 4u+9+2e}, V {4u+8..4u+11}
    {
      int t0 = 4 * u + 8 + 2 * e; if (t0 > 63) t0 = 63;
      int t1 = 4 * u + 9 + 2 * e; if (t1 > 63) t1 = 63;
      kcur0a = *reinterpret_cast<const int4*>(&kcbase[(size_t)((t0 << 5) + krow0) * 2048]);
      kcur0b = *reinterpret_cast<const int4*>(&kcbase[(size_t)((t0 << 5) + krow0 + 4) * 2048]);
      kcur1a = *reinterpret_cast<const int4*>(&kcbase[(size_t)((t1 << 5) + krow0) * 2048]);
      kcur1b = *reinterpret_cast<const int4*>(&kcbase[(size_t)((t1 << 5) + krow0 + 4) * 2048]);
      int tv0 = 4 * u + 8;  if (tv0 > 63) tv0 = 63;
      int tv1 = 4 * u + 9;  if (tv1 > 63) tv1 = 63;
      int tv2 = 4 * u + 10; if (tv2 > 63) tv2 = 63;
      int tv3 = 4 * u + 11; if (tv3 > 63) tv3 = 63;
      vcur0 = *reinterpret_cast<const int4*>(&vtbase[tv0 << 5]);
      vcur1 = *reinterpret_cast<const int4*>(&vtbase[tv1 << 5]);
      vcur2 = *reinterpret_cast<const int4*>(&vtbase[tv2 << 5]);
      vcur3 = *reinterpret_cast<const int4*>(&vtbase[tv3 << 5]);
    }
    // 3/4. subtile A then B (separate guarded blocks; krro loaded on demand)
    {
      const int tA = 4 * u + 2 * e;
      if (tA < nt_w) {
        short8 krfA[4];
        #pragma unroll
        for (int f = 0; f < 4; ++f)
          krfA[f] = *reinterpret_cast<const short8*>(
              &krro[(bsb + (tA << 5) + l31) * 64 + f * 16 + hi8]);
        process_tile(tA, krfA);
      }
      const int tB = tA + 1;
      if (tB < nt_w) {
        short8 krfB[4];
        #pragma unroll
        for (int f = 0; f < 4; ++f)
          krfB[f] = *reinterpret_cast<const short8*>(
              &krro[(bsb + (tB << 5) + l31) * 64 + f * 16 + hi8]);
        process_tile(tB, krfB);
      }
    }
    // 5. sync: LDS writes visible; in-flight register loads cross the barrier
    asm volatile("s_waitcnt lgkmcnt(0)" ::: "memory");
    __builtin_amdgcn_s_barrier();
  }

  __syncthreads();  // full drain before LDS reuse as merge scratch

  // ---- flash merge of parity groups; acc = O^T[v][q=l31], m/l lane-local ----
  if (e == 1) {
    #pragma unroll
    for (int a = 0; a < 4; ++a)
      #pragma unroll
      for (int r = 0; r < 16; ++r) {
        int v = 32 * a + (r & 3) + ((r >> 2) << 3) + (hi << 2);
        Msh[((s << 7) + v) * 33 + l31] = acc[a][r];
      }
    if (hi == 0) {
      Msh[16896 + ((s << 5) + l31) * 2 + 0] = mrun;
      Msh[16896 + ((s << 5) + l31) * 2 + 1] = lsum;
    }
  }
  __syncthreads();
  if (e == 0) {
    float m1 = Msh[16896 + ((s << 5) + l31) * 2 + 0];
    float l1 = Msh[16896 + ((s << 5) + l31) * 2 + 1];
    float mm = fmaxf(mrun, m1);
    float ea = exp2_raw(mrun - mm), eb = exp2_raw(m1 - mm);
    float linv = 1.f / (lsum * ea + l1 * eb);
    float al = ea * linv, be = eb * linv;
    #pragma unroll
    for (int a = 0; a < 4; ++a)
      #pragma unroll
      for (int r = 0; r < 16; ++r) {
        int v = 32 * a + (r & 3) + ((r >> 2) << 3) + (hi << 2);
        float part = Msh[((s << 7) + v) * 33 + l31];
        acc[a][r] = acc[a][r] * al + part * be;
      }
    unsigned int* Tb = reinterpret_cast<unsigned int*>(smem) + s * 4224;
    #pragma unroll
    for (int a = 0; a < 4; ++a)
      #pragma unroll
      for (int j = 0; j < 8; ++j) {
        unsigned int word = cvt_pk_bf16(acc[a][2 * j], acc[a][2 * j + 1]);
        int wc = 16 * a + 2 * hi + (j & 1) + 4 * (j >> 1);
        Tb[l31 * 68 + wc] = word;
      }
    const unsigned char* Tbb = reinterpret_cast<const unsigned char*>(Tb);
    #pragma unroll
    for (int u2 = 0; u2 < 8; ++u2) {
      int qr = (u2 << 2) + (lane >> 4);
      int4 rd = *reinterpret_cast<const int4*>(&Tbb[qr * 272 + (lane & 15) * 16]);
      *reinterpret_cast<int4*>(
          &attn_out[(bsb + q0 + qr) * 2048 + h * 128 + (lane & 15) * 8]) = rd;
    }
  }
}

// ---------------- launch ----------------

extern "C" void kernel_launch(void* const* d_in, const int* in_sizes, int n_in,
                              void* d_out, int out_size, void* d_ws, size_t ws_size,
                              hipStream_t stream) {
  (void)in_sizes; (void)n_in; (void)out_size; (void)ws_size;
  const float* x = (const float*)d_in[0];
  const float* freq = (const float*)d_in[1];
  // d_in[2] = mask: always causal tril -> handled analytically
  const float* w_dq = (const float*)d_in[3];
  const float* b_dq = (const float*)d_in[4];
  const float* w_uq = (const float*)d_in[5];
  const float* b_uq = (const float*)d_in[6];
  const float* w_qr = (const float*)d_in[7];
  const float* b_qr = (const float*)d_in[8];
  const float* w_dkv = (const float*)d_in[9];
  const float* b_dkv = (const float*)d_in[10];
  const float* w_ukv = (const float*)d_in[11];
  const float* b_ukv = (const float*)d_in[12];
  const float* w_kr = (const float*)d_in[13];
  const float* b_kr = (const float*)d_in[14];
  const float* w_o = (const float*)d_in[15];
  const float* b_o = (const float*)d_in[16];

  char* ws = (char*)d_ws;
  size_t off = 0;
  auto alloc = [&](size_t bytes) {
    char* p = ws + off;
    off += (bytes + 255) & ~(size_t)255;
    return p;
  };
  unsigned short* x_bf   = (unsigned short*)alloc((size_t)4096 * 2048 * 2);
  unsigned short* wd_t   = (unsigned short*)alloc((size_t)1344 * 2048 * 2);
  unsigned short* wqc_t  = (unsigned short*)alloc((size_t)3072 * 768 * 2);
  unsigned short* wukv_t = (unsigned short*)alloc((size_t)4096 * 512 * 2);
  unsigned short* wo_t   = (unsigned short*)alloc((size_t)2048 * 2048 * 2);
  float* tab             = (float*)alloc((size_t)2048 * 32 * 2 * 4);
  float* bcat            = (float*)alloc((size_t)3072 * 4);
  float* ball            = (float*)alloc((size_t)1344 * 4);
  unsigned short* c_all  = (unsigned short*)alloc((size_t)4096 * 1344 * 2);
  unsigned short* krro   = (unsigned short*)alloc((size_t)4096 * 64 * 2);
  unsigned short* q_raw  = (unsigned short*)alloc((size_t)4096 * 3072 * 2);
  unsigned short* kc     = (unsigned short*)alloc((size_t)4096 * 2048 * 2);
  unsigned short* v_t    = (unsigned short*)alloc((size_t)4096 * 2048 * 2);
  unsigned short* attn   = (unsigned short*)alloc((size_t)4096 * 2048 * 2);

  // A: x cast + down-proj weight transposes + rope table + bias concat
  k_prep_a<<<dim3(9138), dim3(256), 0, stream>>>(
      x, freq, w_dq, w_dkv, w_kr, b_uq, b_qr, b_dq, b_dkv, b_kr,
      x_bf, wd_t, tab, bcat, ball);

  // B: merged down-projection GEMM + up/out weight transposes (tail-filled)
  k_down<<<dim3(2464), dim3(256), 0, stream>>>(
      x_bf, wd_t, ball, c_all, w_uq, w_qr, w_ukv, w_o, wqc_t, wukv_t, wo_t);

  // C: upQ GEMM + upKV split GEMM + rope_kr
  k_up<<<dim3(2304), dim3(256), 0, stream>>>(
      c_all, wqc_t, bcat, q_raw, wukv_t, b_ukv, kc, v_t, tab, krro);

  // D: fused causal attention (round-13 best-known config)
  k_mla_attn<<<dim3(512), dim3(512), 0, stream>>>(q_raw, kc, v_t, krro, tab, attn);

  // E: output projection -> f32
  k_out<<<dim3(512), dim3(256), 0, stream>>>(attn, wo_t, b_o, (float*)d_out);
}